// Round 5
// baseline (608.771 us; speedup 1.0000x reference)
//
#include <hip/hip_runtime.h>
#include <cstdint>
#include <cstddef>

typedef _Float16 f16;
typedef _Float16 f16x8 __attribute__((ext_vector_type(8)));
typedef float f32x4 __attribute__((ext_vector_type(4)));

// ---------------- helpers ----------------

__device__ __forceinline__ void gload16(const void* g, void* l) {
  // async global->LDS, 16B per lane; LDS dest must be wave-uniform base + lane*16
  __builtin_amdgcn_global_load_lds((const __attribute__((address_space(1))) void*)g,
                                   (__attribute__((address_space(3))) void*)l, 16, 0, 0);
}

__device__ __forceinline__ uint32_t packh2(float a, float b) {
  f16 ha = (f16)a, hb = (f16)b;
  uint16_t ua = __builtin_bit_cast(uint16_t, ha);
  uint16_t ub = __builtin_bit_cast(uint16_t, hb);
  return (uint32_t)ua | ((uint32_t)ub << 16);
}

// ---------------- prep ----------------
// lut: plain K-tiled [kt][o][kk] (kt = K-chunk of 64, o = out channel, kk = ck&63)
//   -> B panel per chunk is a contiguous 32 KB block; fragments read DIRECTLY
//      from global (L2-resident, 2 MB) by the fused kernel.
// centK[conv][kt][640]: per-chunk centroids pre-scaled by 2 (576 floats,
//   layout [cg*2+half][8 cw][9]) then 64 cn values ([cg*16+half*8+k]).
__global__ __launch_bounds__(256) void prep_kernel(
    const float* __restrict__ cent1, const float* __restrict__ wsub1,
    const float* __restrict__ cent2, const float* __restrict__ wsub2,
    const float* __restrict__ g1, const float* __restrict__ be1,
    const float* __restrict__ mu1, const float* __restrict__ va1,
    const float* __restrict__ g2, const float* __restrict__ be2,
    const float* __restrict__ mu2, const float* __restrict__ va2,
    f16* __restrict__ lut1, f16* __restrict__ lut2,
    float* __restrict__ centK1, float* __restrict__ centK2,
    float* __restrict__ bn1i, float* __restrict__ bn1a,
    float* __restrict__ bn2i, float* __restrict__ bn2a,
    float* __restrict__ pool)
{
  int bx = blockIdx.x, t = threadIdx.x;
  if (bx < 8192) {
    int conv = bx >> 12, ck = bx & 4095, c = ck >> 4;
    const float* cent = conv ? cent2 : cent1;
    const float* wsub = conv ? wsub2 : wsub1;
    f16* lut = conv ? lut2 : lut1;
    float s = 0.f;
#pragma unroll
    for (int sv = 0; sv < 9; ++sv)
      s += cent[ck*9 + sv] * wsub[(c*9 + sv)*256 + t];
    lut[(size_t)(ck >> 6)*16384 + (size_t)t*64 + (ck & 63)] = (f16)s;
  } else if (bx < 8320) {
    int base = bx - 8192;
    int conv = base >> 6, kt = base & 63;
    const float* cent = conv ? cent2 : cent1;
    float* centK = conv ? centK2 : centK1;
    for (int f = t; f < 640; f += 256) {
      float v;
      if (f < 576) {
        int g = f / 72, w = f % 72;           // g = cg*2+half
        int cg = g >> 1, hf = g & 1;
        int kl = w / 9, s = w % 9;
        int c = kt*4 + cg, k = hf*8 + kl;
        v = 2.f * cent[(c*16 + k)*9 + s];
      } else {
        int j = f - 576;
        int c = kt*4 + (j >> 4), k = j & 15;
        float ss = 0.f;
#pragma unroll
        for (int s = 0; s < 9; ++s) { float a = cent[(c*16 + k)*9 + s]; ss += a*a; }
        v = ss;
      }
      centK[(size_t)kt*640 + f] = v;
    }
  } else {
    for (int j = 0; j < 16; ++j)
      pool[j*256 + t] = 0.f;                  // ws is re-poisoned 0xAA every launch
    float i1 = g1[t] * rsqrtf(va1[t] + 1e-5f);
    bn1i[t] = i1; bn1a[t] = be1[t] - mu1[t]*i1;
    float i2 = g2[t] * rsqrtf(va2[t] + 1e-5f);
    bn2i[t] = i2; bn2a[t] = be2[t] - mu2[t]*i2;
  }
}

// ---------------- fused attn+GEMM layer (K-split x4) ----------------
// Grid (196, 4): blockIdx.x = 64-row M-tile, blockIdx.y = kh = K quarter
// (64 channels = 16 chunks of 4ch x 16cw). 256 threads = 4 waves.
// Occupancy: __launch_bounds__(256,3) -> 3 independent blocks/CU (12 waves in
// 3 barrier groups) so waves of other blocks fill each group's latency stalls
// (the R4 structure had ONE 8-wave group per CU and sat idle).
// Per chunk: producers (thread = 2 positions x channel x cw-half) compute the
// 64x64 fp16 attn tile -> LDS As (row pad 72 f16 = 144B == 4 banks mod 32 ->
// conflict-free b128 writes AND reads, no swizzle); consumers run
// mfma_f32_16x16x32_f16 with A from LDS, B direct from the K-tiled lut (L2).
// Centroids staged async via global_load_lds one chunk ahead. Output = raw
// f32 partial sums (BN applied by reduce_kernel after the 4 partials add).
// SRC==0: src is x, NCHW [16][256][28][28]. SRC==1: src is y1, NHWC [12544][256].
template<int SRC>
__global__ __launch_bounds__(256, 3) void fused_kernel(
    const float* __restrict__ src, const float* __restrict__ centK,
    const f16* __restrict__ lut, float* __restrict__ Ypart)
{
  __shared__ __align__(16) f16 As[2][64*72];    // 2 x 9 KB, padded rows
  __shared__ __align__(16) float Cs[2][640];    // 2 x 2.5 KB

  int t = threadIdx.x;
  int lane = t & 63;
  int wn = t >> 6;                      // wave = N-slice of 64 outputs
  int fm = lane & 15, fq = lane >> 4;

  int kh = blockIdx.y;                  // K quarter: chunks g0..g0+15
  int g0 = kh*16;
  int row0 = blockIdx.x * 64;

  // producer role: thread -> (pos pair {p2, p2+32}, cg, hf)
  int p2 = t >> 3, cg = (t >> 1) & 3, hf = t & 1;
  int c0 = kh*64 + cg;                  // first channel this thread touches

  const float* pbase[2]; int offc[2][9]; float msk[2][9];
#pragma unroll
  for (int i = 0; i < 2; ++i) {
    int P = row0 + p2 + i*32;
    int b = P / 784, n = P % 784, h = n / 28, w = n % 28;
    pbase[i] = (SRC == 0) ? src + ((size_t)b*256 + c0)*784
                          : src + (size_t)b*200704 + c0;
#pragma unroll
    for (int dh = 0; dh < 3; ++dh)
#pragma unroll
      for (int dw = 0; dw < 3; ++dw) {
        int hh = h + dh - 1, ww = w + dw - 1;
        bool ok = (hh >= 0) && (hh < 28) && (ww >= 0) && (ww < 28);
        int o = ok ? (hh*28 + ww) : 0;
        offc[i][dh*3+dw] = (SRC == 0) ? o : o*256;
        msk[i][dh*3+dw] = ok ? 1.f : 0.f;
      }
  }
  const int pstep = (SRC == 0) ? 4*784 : 4;     // advance 4 channels

  f32x4 acc[4][4] = {};

  auto stageC = [&](int g, int buf) {
    if (t < 160) gload16(centK + (size_t)g*640 + t*4, &Cs[buf][0] + t*4);
  };

  auto loadPN = [&](int kt, float* pn) {        // masked patch, 2 positions
#pragma unroll
    for (int i = 0; i < 2; ++i)
#pragma unroll
      for (int s = 0; s < 9; ++s)
        pn[i*9 + s] = pbase[i][offc[i][s] + kt*pstep] * msk[i][s];
  };

  auto attn_store = [&](const float* Cb, const float* pn, f16* Ab) {
    const float* ce  = Cb + (cg*2 + hf)*72;     // 2x-scaled centroids (LDS)
    const float* cnl = Cb + 576 + cg*16 + hf*8; // cn (LDS)
    float e0[8], e1[8];
#pragma unroll
    for (int kq = 0; kq < 2; ++kq) {            // 4-codeword batches
      f32x4 cr[9];
#pragma unroll
      for (int i = 0; i < 9; ++i) cr[i] = *(const f32x4*)(ce + kq*36 + i*4);
      f32x4 cc = *(const f32x4*)(cnl + kq*4);
#pragma unroll
      for (int k = 0; k < 4; ++k) {
        float d0 = 0.f, d1 = 0.f;
#pragma unroll
        for (int s = 0; s < 9; ++s) {
          int i = k*9 + s;                      // compile-time after unroll
          float cv = cr[i >> 2][i & 3];
          d0 += pn[s]*cv;
          d1 += pn[9+s]*cv;
        }
        e0[kq*4+k] = d0 - cc[k];                // ||p||^2 cancels in softmax
        e1[kq*4+k] = d1 - cc[k];
      }
    }
    float mx0 = e0[0], mx1 = e1[0];
#pragma unroll
    for (int k = 1; k < 8; ++k) { mx0 = fmaxf(mx0, e0[k]); mx1 = fmaxf(mx1, e1[k]); }
    mx0 = fmaxf(mx0, __shfl_xor(mx0, 1));       // combine cw-halves (lane pair)
    mx1 = fmaxf(mx1, __shfl_xor(mx1, 1));
    float s0 = 0.f, s1 = 0.f;
#pragma unroll
    for (int k = 0; k < 8; ++k) {
      e0[k] = __expf(e0[k] - mx0); s0 += e0[k];
      e1[k] = __expf(e1[k] - mx1); s1 += e1[k];
    }
    s0 += __shfl_xor(s0, 1);
    s1 += __shfl_xor(s1, 1);
    float r0 = 1.f/s0, r1 = 1.f/s1;
    int col = (cg*2 + hf)*8;                    // k within chunk = cg*16+hf*8+j
    *(uint4*)(Ab + (size_t)p2*72 + col) =
        make_uint4(packh2(e0[0]*r0, e0[1]*r0), packh2(e0[2]*r0, e0[3]*r0),
                   packh2(e0[4]*r0, e0[5]*r0), packh2(e0[6]*r0, e0[7]*r0));
    *(uint4*)(Ab + (size_t)(p2 + 32)*72 + col) =
        make_uint4(packh2(e1[0]*r1, e1[1]*r1), packh2(e1[2]*r1, e1[3]*r1),
                   packh2(e1[4]*r1, e1[5]*r1), packh2(e1[6]*r1, e1[7]*r1));
  };

  auto compute = [&](const f16* Ab, int g) {
    const f16* bp = lut + (size_t)g*16384 + (size_t)(wn*64 + fm)*64;
#pragma unroll
    for (int ks = 0; ks < 2; ++ks) {
      f16x8 af[4], bf[4];
#pragma unroll
      for (int m = 0; m < 4; ++m)
        af[m] = *(const f16x8*)(Ab + (m*16 + fm)*72 + (ks*4 + fq)*8);
#pragma unroll
      for (int nn = 0; nn < 4; ++nn)
        bf[nn] = *(const f16x8*)(bp + nn*1024 + ks*32 + fq*8);
#pragma unroll
      for (int m = 0; m < 4; ++m)
#pragma unroll
        for (int nn = 0; nn < 4; ++nn)
          acc[m][nn] = __builtin_amdgcn_mfma_f32_16x16x32_f16(af[m], bf[nn], acc[m][nn], 0, 0, 0);
    }
  };

  // prologue
  stageC(g0, 0);
  stageC(g0 + 1, 1);
  {
    float pn[18];
    loadPN(0, pn);
    __syncthreads();                    // C0/C1 landed (vmcnt drain)
    attn_store(&Cs[0][0], pn, &As[0][0]);
  }
#pragma unroll 1
  for (int kt = 0; kt < 16; ++kt) {
    __syncthreads();                    // A(kt) visible; C(kt+1) landed
    float pn2[18];
    if (kt < 15) {
      loadPN(kt + 1, pn2);              // issue early; consumed after compute
      if (kt < 14) stageC(g0 + kt + 2, kt & 1);
    }
    compute(&As[kt & 1][0], g0 + kt);
    if (kt < 15) attn_store(&Cs[(kt + 1) & 1][0], pn2, &As[(kt + 1) & 1][0]);
  }

  // epilogue: raw partial sums; C/D layout col=lane&15, row=fq*4+r
  float* Yp = Ypart + (size_t)kh*3211264;
#pragma unroll
  for (int nn = 0; nn < 4; ++nn) {
    int colg = wn*64 + nn*16 + fm;
#pragma unroll
    for (int m = 0; m < 4; ++m) {
      int rowg = row0 + m*16 + fq*4;
#pragma unroll
      for (int r = 0; r < 4; ++r)
        Yp[(size_t)(rowg + r)*256 + colg] = acc[m][nn][r];
    }
  }
}

// ---------------- reduce K-split partials + BN (+ReLU) ----------------
template<bool RELU>
__global__ __launch_bounds__(256) void reduce_kernel(
    const float* __restrict__ P, const float* __restrict__ inv,
    const float* __restrict__ add, float* __restrict__ y)
{
  size_t i = (size_t)blockIdx.x*256 + threadIdx.x;
  int c = threadIdx.x;                  // layout [12544][256]: i % 256 == t
  float v = P[i] + P[i + 3211264] + P[i + 6422528] + P[i + 9633792];
  v = v*inv[c] + add[c];
  y[i] = RELU ? fmaxf(v, 0.f) : v;
}

// ---------------- global average pool (partial sums, atomics) ----------------
__global__ __launch_bounds__(256) void pool_kernel(const float* __restrict__ y2,
                                                   float* __restrict__ pool)
{
  int b = blockIdx.x, t = threadIdx.x;
  int r0 = blockIdx.y * 112;
  float s = 0.f;
  for (int r = 0; r < 112; ++r)
    s += y2[((size_t)b*784 + r0 + r)*256 + t];
  atomicAdd(&pool[b*256 + t], s);
}

// ---------------- SE MLP: scale = sigmoid(relu(mean @ w1 + b1) @ w2 + b2) ----------------
__global__ __launch_bounds__(256) void se_kernel(
    const float* __restrict__ pool, const float* __restrict__ w1, const float* __restrict__ b1,
    const float* __restrict__ w2, const float* __restrict__ b2, float* __restrict__ scale)
{
  __shared__ float m[256];
  __shared__ float hbuf[16];
  int b = blockIdx.x, t = threadIdx.x;
  m[t] = pool[b*256 + t] * (1.f/784.f);
  __syncthreads();
  if (t < 16) {
    float a = b1[t];
    for (int o = 0; o < 256; ++o) a += m[o]*w1[o*16 + t];
    hbuf[t] = fmaxf(a, 0.f);
  }
  __syncthreads();
  float a = b2[t];
#pragma unroll
  for (int jj = 0; jj < 16; ++jj) a += hbuf[jj]*w2[jj*256 + t];
  scale[b*256 + t] = 1.f/(1.f + __expf(-a));
}

// ---------------- final: out = relu(y2 * scale + x), NCHW ----------------
__global__ __launch_bounds__(256) void final_kernel(
    const float* __restrict__ y2, const float* __restrict__ scale,
    const float* __restrict__ x, float* __restrict__ out)
{
  int idx = blockIdx.x*256 + threadIdx.x;
  int b = idx / 200704, rem = idx % 200704;
  int o = rem / 784, hw = rem % 784;
  float v = y2[((size_t)b*784 + hw)*256 + o]*scale[b*256 + o] + x[idx];
  out[idx] = fmaxf(v, 0.f);
}

// ---------------- launch ----------------
extern "C" void kernel_launch(void* const* d_in, const int* in_sizes, int n_in,
                              void* d_out, int out_size, void* d_ws, size_t ws_size,
                              hipStream_t stream) {
  const float* x     = (const float*)d_in[0];
  const float* cent1 = (const float*)d_in[1];
  const float* wsub1 = (const float*)d_in[2];
  const float* g1    = (const float*)d_in[3];
  const float* be1   = (const float*)d_in[4];
  const float* mu1   = (const float*)d_in[5];
  const float* va1   = (const float*)d_in[6];
  const float* cent2 = (const float*)d_in[7];
  const float* wsub2 = (const float*)d_in[8];
  const float* g2    = (const float*)d_in[9];
  const float* be2   = (const float*)d_in[10];
  const float* mu2   = (const float*)d_in[11];
  const float* va2   = (const float*)d_in[12];
  const float* sw1   = (const float*)d_in[13];
  const float* sb1   = (const float*)d_in[14];
  const float* sw2   = (const float*)d_in[15];
  const float* sb2   = (const float*)d_in[16];
  float* out = (float*)d_out;

  char* ws = (char*)d_ws;
  float* centK1 = (float*)(ws + 0);               // 163,840
  float* centK2 = (float*)(ws + 163840);          // 163,840
  float* bn1i   = (float*)(ws + 327680);
  float* bn1a   = (float*)(ws + 328704);
  float* bn2i   = (float*)(ws + 329728);
  float* bn2a   = (float*)(ws + 330752);
  float* pool   = (float*)(ws + 331776);          // 16 KB
  float* scale  = (float*)(ws + 348160);          // 16 KB
  f16*   lut1   = (f16*)(ws + 2097152);           // 2 MB (K-tiled)
  f16*   lut2   = (f16*)(ws + 4194304);           // 2 MB
  float* y1     = (float*)(ws + 6291456);         // 12,845,056
  float* y2     = (float*)(ws + 19136512);        // 12,845,056
  float* ypart  = (float*)(ws + 31981568);        // 4 x 12,845,056 = 51,380,224
                                                  // (reused for both layers; end ~79.5 MB)

  prep_kernel<<<8321, 256, 0, stream>>>(cent1, wsub1, cent2, wsub2,
                                        g1, be1, mu1, va1, g2, be2, mu2, va2,
                                        lut1, lut2, centK1, centK2,
                                        bn1i, bn1a, bn2i, bn2a, pool);
  fused_kernel<0><<<dim3(196, 4), 256, 0, stream>>>(x,  centK1, lut1, ypart);
  reduce_kernel<true ><<<12544, 256, 0, stream>>>(ypart, bn1i, bn1a, y1);
  fused_kernel<1><<<dim3(196, 4), 256, 0, stream>>>(y1, centK2, lut2, ypart);
  reduce_kernel<false><<<12544, 256, 0, stream>>>(ypart, bn2i, bn2a, y2);
  pool_kernel<<<dim3(16, 7), 256, 0, stream>>>(y2, pool);
  se_kernel<<<16, 256, 0, stream>>>(pool, sw1, sb1, sw2, sb2, scale);
  final_kernel<<<12544, 256, 0, stream>>>(y2, scale, x, out);
}

// Round 7
// 490.415 us; speedup vs baseline: 1.2413x; 1.2413x over previous
//
#include <hip/hip_runtime.h>
#include <cstdint>
#include <cstddef>

typedef _Float16 f16;
typedef _Float16 f16x8 __attribute__((ext_vector_type(8)));
typedef float f32x4 __attribute__((ext_vector_type(4)));

// ---------------- helpers ----------------

__device__ __forceinline__ void gload16(const void* g, void* l) {
  // async global->LDS, 16B per lane; LDS dest must be wave-uniform base + lane*16
  __builtin_amdgcn_global_load_lds((const __attribute__((address_space(1))) void*)g,
                                   (__attribute__((address_space(3))) void*)l, 16, 0, 0);
}

__device__ __forceinline__ uint32_t packh2(float a, float b) {
  f16 ha = (f16)a, hb = (f16)b;
  uint16_t ua = __builtin_bit_cast(uint16_t, ha);
  uint16_t ub = __builtin_bit_cast(uint16_t, hb);
  return (uint32_t)ua | ((uint32_t)ub << 16);
}

// ---------------- prep ----------------
// lut: K-tiled AND pre-swizzled for linear global_load_lds staging:
//   logical (kt, o, kk) stored at [kt][o][ ((kk>>3)^(o&7))*8 + (kk&7) ]
//   -> consumers read with the same XOR and get conflict-free ds_read_b128
//   (this exact scheme measured 0 bank conflicts in R4).
// centK[conv][kt][640]: per-chunk centroids pre-scaled by 2, layout
//   [cg][cw(16)][s(9)] (576 floats), then 64 cn values [cg*16+cw].
__global__ __launch_bounds__(256) void prep_kernel(
    const float* __restrict__ cent1, const float* __restrict__ wsub1,
    const float* __restrict__ cent2, const float* __restrict__ wsub2,
    const float* __restrict__ g1, const float* __restrict__ be1,
    const float* __restrict__ mu1, const float* __restrict__ va1,
    const float* __restrict__ g2, const float* __restrict__ be2,
    const float* __restrict__ mu2, const float* __restrict__ va2,
    f16* __restrict__ lut1, f16* __restrict__ lut2,
    float* __restrict__ centK1, float* __restrict__ centK2,
    float* __restrict__ bn1i, float* __restrict__ bn1a,
    float* __restrict__ bn2i, float* __restrict__ bn2a,
    float* __restrict__ pool)
{
  int bx = blockIdx.x, t = threadIdx.x;
  if (bx < 8192) {
    int conv = bx >> 12, ck = bx & 4095, c = ck >> 4;
    const float* cent = conv ? cent2 : cent1;
    const float* wsub = conv ? wsub2 : wsub1;
    f16* lut = conv ? lut2 : lut1;
    float s = 0.f;
#pragma unroll
    for (int sv = 0; sv < 9; ++sv)
      s += cent[ck*9 + sv] * wsub[(c*9 + sv)*256 + t];
    int kk = ck & 63;
    lut[(size_t)(ck >> 6)*16384 + (size_t)t*64 + (((kk >> 3) ^ (t & 7))*8) + (kk & 7)] = (f16)s;
  } else if (bx < 8320) {
    int base = bx - 8192;
    int conv = base >> 6, kt = base & 63;
    const float* cent = conv ? cent2 : cent1;
    float* centK = conv ? centK2 : centK1;
    for (int f = t; f < 640; f += 256) {
      float v;
      if (f < 576) {
        int cg = f / 144, rem = f % 144;
        int cw = rem / 9, s = rem % 9;
        v = 2.f * cent[((kt*4 + cg)*16 + cw)*9 + s];
      } else {
        int j = f - 576;
        int c = kt*4 + (j >> 4), k = j & 15;
        float ss = 0.f;
#pragma unroll
        for (int s = 0; s < 9; ++s) { float a = cent[(c*16 + k)*9 + s]; ss += a*a; }
        v = ss;
      }
      centK[(size_t)kt*640 + f] = v;
    }
  } else {
    for (int j = 0; j < 16; ++j)
      pool[j*256 + t] = 0.f;                  // ws is re-poisoned 0xAA every launch
    float i1 = g1[t] * rsqrtf(va1[t] + 1e-5f);
    bn1i[t] = i1; bn1a[t] = be1[t] - mu1[t]*i1;
    float i2 = g2[t] * rsqrtf(va2[t] + 1e-5f);
    bn2i[t] = i2; bn2a[t] = be2[t] - mu2[t]*i2;
  }
}

// ---------------- fused attn+GEMM layer: producer/consumer wave pipeline ----------------
// Block = 64 positions x 256 outputs, K = 4096 in 64 chunks (4 ch x 16 cw).
// NO __syncthreads in the main loop. 8 waves:
//   waves 4..7 = PRODUCERS: wave p owns tiles kt = p (mod 4) -> A-ring slot p.
//     Lane = one fixed position. 4 passes per tile (one channel each): 16 dots
//     of 9 vs wave-uniform (scalar-load) centroids, in-lane softmax16, pack,
//     2 swizzled b128 LDS writes. pn patch floats double-buffered one pass
//     ahead. Protocol: spin consumed[p] >= 4*my (acquire), produce, lane0
//     store ready[p] = kt (release; wave-wide lgkmcnt drain covers all lanes).
//   waves 0..3 = CONSUMERS: wave wn owns output cols wn*64..+63. Per tile:
//     spin ready[kt&3] >= kt (acquire), vmcnt(0) for its OWN B-slice stage
//     (private 8 KB, global_load_lds, double buffered), 8 ds_read_b128 +
//     32 mfma, lane0 fetch_add consumed[kt&3] (release) -- LANE0 ONLY: the
//     R6 all-lane fetch_add bumped the counter 64x/wave, letting producers
//     overwrite slots while other consumer waves were still reading (the
//     absmax=36 race). Then stage B(kt+1).
// SRC==0: src is x, NCHW [16][256][28][28]. SRC==1: src is y1, NHWC [12544][256].
template<int SRC, bool RELU>
__global__ __launch_bounds__(512) void fused_kernel(
    const float* __restrict__ src, const float* __restrict__ centK,
    const f16* __restrict__ lut,
    const float* __restrict__ inv, const float* __restrict__ add,
    float* __restrict__ Y)
{
  __shared__ __align__(16) f16 As[4][4096];      // 4-slot A ring, 8 KB each
  __shared__ __align__(16) f16 Bs[4][2][4096];   // per-consumer private B dbuf
  __shared__ int ready[4];                       // highest tile index written to slot
  __shared__ int consumed[4];                    // consumer-wave completions for slot

  int t = threadIdx.x, lane = t & 63, wave = t >> 6;
  if (t < 4) { ready[t] = -1; consumed[t] = 0; }
  __syncthreads();                               // flags visible to all waves

  int row0 = blockIdx.x * 64;

  if (wave < 4) {
    // ================= consumer =================
    int wn = wave, fm = lane & 15, fq = lane >> 4;
    f32x4 acc[4][4] = {};
    auto stageB = [&](int kt) {                  // own 8 KB slice: rows wn*64..+63
      const f16* sp = lut + (size_t)kt*16384 + (size_t)wn*4096 + lane*8;
      f16* dp = &Bs[wn][kt & 1][0] + lane*8;
#pragma unroll
      for (int i = 0; i < 8; ++i) gload16(sp + i*512, dp + i*512);
    };
    stageB(0);
#pragma unroll 1
    for (int kt = 0; kt < 64; ++kt) {
      int s = kt & 3;
      while (__hip_atomic_load(&ready[s], __ATOMIC_ACQUIRE, __HIP_MEMORY_SCOPE_WORKGROUP) < kt)
        __builtin_amdgcn_s_sleep(2);
      asm volatile("s_waitcnt vmcnt(0)" ::: "memory");   // own B(kt) stage landed
      const f16* Ab = &As[s][0];
      const f16* Bb = &Bs[wn][kt & 1][0];
#pragma unroll
      for (int ks = 0; ks < 2; ++ks) {
        int co = ((ks*4 + fq) ^ (fm & 7)) * 8;           // XOR de-swizzle (A and B)
        f16x8 af[4], bf[4];
#pragma unroll
        for (int m = 0; m < 4; ++m)
          af[m] = *(const f16x8*)(Ab + (m*16 + fm)*64 + co);
#pragma unroll
        for (int nn = 0; nn < 4; ++nn)
          bf[nn] = *(const f16x8*)(Bb + (nn*16 + fm)*64 + co);
#pragma unroll
        for (int m = 0; m < 4; ++m)
#pragma unroll
          for (int nn = 0; nn < 4; ++nn)
            acc[m][nn] = __builtin_amdgcn_mfma_f32_16x16x32_f16(af[m], bf[nn], acc[m][nn], 0, 0, 0);
      }
      // release by lane 0 ONLY (one increment per wave). The release's
      // wave-wide lgkmcnt(0) drain orders ALL lanes' A ds_reads before it.
      if (lane == 0)
        __hip_atomic_fetch_add(&consumed[s], 1, __ATOMIC_RELEASE, __HIP_MEMORY_SCOPE_WORKGROUP);
      if (kt < 63) stageB(kt + 1);               // latency hides under next spin
    }
    // epilogue: C/D layout col=lane&15, row=fq*4+r; fused BN (+ReLU)
#pragma unroll
    for (int nn = 0; nn < 4; ++nn) {
      int colg = wn*64 + nn*16 + fm;
      float iv = inv[colg], ad = add[colg];
#pragma unroll
      for (int m = 0; m < 4; ++m) {
        int rowg = row0 + m*16 + fq*4;
#pragma unroll
        for (int r = 0; r < 4; ++r) {
          float v = acc[m][nn][r]*iv + ad;
          if (RELU) v = fmaxf(v, 0.f);
          Y[(size_t)(rowg + r)*256 + colg] = v;
        }
      }
    }
  } else {
    // ================= producer =================
    int p = wave - 4;
    int P = row0 + lane;                        // lane = one fixed position
    int b = P / 784, n = P % 784, h = n / 28, w = n % 28;
    const float* pb = src + (size_t)b*200704;   // NCHW and NHWC share batch stride
    int offc[9]; float msk[9];
#pragma unroll
    for (int dh = 0; dh < 3; ++dh)
#pragma unroll
      for (int dw = 0; dw < 3; ++dw) {
        int hh = h + dh - 1, ww = w + dw - 1;
        bool ok = (hh >= 0) && (hh < 28) && (ww >= 0) && (ww < 28);
        int o = ok ? (hh*28 + ww) : 0;
        offc[dh*3+dw] = (SRC == 0) ? o : o*256;
        msk[dh*3+dw] = ok ? 1.f : 0.f;
      }
    const int cstep = (SRC == 0) ? 784 : 1;     // element stride per channel

    float pn[2][9];
    auto issue_pn = [&](int c, int buf) {
#pragma unroll
      for (int s2 = 0; s2 < 9; ++s2) pn[buf][s2] = pb[offc[s2] + c*cstep];
    };
    issue_pn(p*4, 0);                           // first pass of first tile

#pragma unroll 1
    for (int my = 0; my < 16; ++my) {
      int kt = my*4 + p;
      const float* cK = centK + (size_t)__builtin_amdgcn_readfirstlane(kt)*640;
      while (__hip_atomic_load(&consumed[p], __ATOMIC_ACQUIRE, __HIP_MEMORY_SCOPE_WORKGROUP) < my*4)
        __builtin_amdgcn_s_sleep(2);
      f16* Ab = &As[p][0];
      int r7 = lane & 7;
#pragma unroll
      for (int cg = 0; cg < 4; ++cg) {
        int cur = cg & 1;
        int cnext = (cg < 3) ? (kt*4 + cg + 1)
                             : ((my < 15) ? (kt + 4)*4 : kt*4 + 3);
        issue_pn(cnext, cur ^ 1);               // prefetch next pass's patch
        const float* cw9 = cK + cg*144;         // wave-uniform -> scalar loads
        const float* cnq = cK + 576 + cg*16;
        float p9[9];
#pragma unroll
        for (int s2 = 0; s2 < 9; ++s2) p9[s2] = pn[cur][s2]*msk[s2];
        float e[16];
#pragma unroll
        for (int k = 0; k < 16; ++k) {
          float d = -cnq[k];                    // cent pre-scaled 2x; ||p||^2 cancels
#pragma unroll
          for (int s2 = 0; s2 < 9; ++s2) d += p9[s2]*cw9[k*9 + s2];
          e[k] = d;
        }
        float mx = e[0];
#pragma unroll
        for (int k = 1; k < 16; ++k) mx = fmaxf(mx, e[k]);
        float sum = 0.f;
#pragma unroll
        for (int k = 0; k < 16; ++k) { e[k] = __expf(e[k] - mx); sum += e[k]; }
        float rs = __builtin_amdgcn_rcpf(sum);
        uint4 q0 = make_uint4(packh2(e[0]*rs,  e[1]*rs),  packh2(e[2]*rs,  e[3]*rs),
                              packh2(e[4]*rs,  e[5]*rs),  packh2(e[6]*rs,  e[7]*rs));
        uint4 q1 = make_uint4(packh2(e[8]*rs,  e[9]*rs),  packh2(e[10]*rs, e[11]*rs),
                              packh2(e[12]*rs, e[13]*rs), packh2(e[14]*rs, e[15]*rs));
        // row = lane; logical chunk cg*2+{0,1} stored at phys ^(row&7): 2 lanes/bank
        *(uint4*)(Ab + lane*64 + (((cg*2)     ^ r7) * 8)) = q0;
        *(uint4*)(Ab + lane*64 + (((cg*2 + 1) ^ r7) * 8)) = q1;
      }
      // release by lane 0 ONLY; wave-wide lgkmcnt drain covers all lanes' writes
      if (lane == 0)
        __hip_atomic_store(&ready[p], kt, __ATOMIC_RELEASE, __HIP_MEMORY_SCOPE_WORKGROUP);
    }
  }
}

// ---------------- global average pool (partial sums, atomics) ----------------
__global__ __launch_bounds__(256) void pool_kernel(const float* __restrict__ y2,
                                                   float* __restrict__ pool)
{
  int b = blockIdx.x, t = threadIdx.x;
  int r0 = blockIdx.y * 112;
  float s = 0.f;
  for (int r = 0; r < 112; ++r)
    s += y2[((size_t)b*784 + r0 + r)*256 + t];
  atomicAdd(&pool[b*256 + t], s);
}

// ---------------- SE MLP: scale = sigmoid(relu(mean @ w1 + b1) @ w2 + b2) ----------------
__global__ __launch_bounds__(256) void se_kernel(
    const float* __restrict__ pool, const float* __restrict__ w1, const float* __restrict__ b1,
    const float* __restrict__ w2, const float* __restrict__ b2, float* __restrict__ scale)
{
  __shared__ float m[256];
  __shared__ float hbuf[16];
  int b = blockIdx.x, t = threadIdx.x;
  m[t] = pool[b*256 + t] * (1.f/784.f);
  __syncthreads();
  if (t < 16) {
    float a = b1[t];
    for (int o = 0; o < 256; ++o) a += m[o]*w1[o*16 + t];
    hbuf[t] = fmaxf(a, 0.f);
  }
  __syncthreads();
  float a = b2[t];
#pragma unroll
  for (int jj = 0; jj < 16; ++jj) a += hbuf[jj]*w2[jj*256 + t];
  scale[b*256 + t] = 1.f/(1.f + __expf(-a));
}

// ---------------- final: out = relu(y2 * scale + x), NCHW ----------------
__global__ __launch_bounds__(256) void final_kernel(
    const float* __restrict__ y2, const float* __restrict__ scale,
    const float* __restrict__ x, float* __restrict__ out)
{
  int idx = blockIdx.x*256 + threadIdx.x;
  int b = idx / 200704, rem = idx % 200704;
  int o = rem / 784, hw = rem % 784;
  float v = y2[((size_t)b*784 + hw)*256 + o]*scale[b*256 + o] + x[idx];
  out[idx] = fmaxf(v, 0.f);
}

// ---------------- launch ----------------
extern "C" void kernel_launch(void* const* d_in, const int* in_sizes, int n_in,
                              void* d_out, int out_size, void* d_ws, size_t ws_size,
                              hipStream_t stream) {
  const float* x     = (const float*)d_in[0];
  const float* cent1 = (const float*)d_in[1];
  const float* wsub1 = (const float*)d_in[2];
  const float* g1    = (const float*)d_in[3];
  const float* be1   = (const float*)d_in[4];
  const float* mu1   = (const float*)d_in[5];
  const float* va1   = (const float*)d_in[6];
  const float* cent2 = (const float*)d_in[7];
  const float* wsub2 = (const float*)d_in[8];
  const float* g2    = (const float*)d_in[9];
  const float* be2   = (const float*)d_in[10];
  const float* mu2   = (const float*)d_in[11];
  const float* va2   = (const float*)d_in[12];
  const float* sw1   = (const float*)d_in[13];
  const float* sb1   = (const float*)d_in[14];
  const float* sw2   = (const float*)d_in[15];
  const float* sb2   = (const float*)d_in[16];
  float* out = (float*)d_out;

  char* ws = (char*)d_ws;
  float* centK1 = (float*)(ws + 0);               // 163,840
  float* centK2 = (float*)(ws + 163840);          // 163,840
  float* bn1i   = (float*)(ws + 327680);
  float* bn1a   = (float*)(ws + 328704);
  float* bn2i   = (float*)(ws + 329728);
  float* bn2a   = (float*)(ws + 330752);
  float* pool   = (float*)(ws + 331776);          // 16 KB
  float* scale  = (float*)(ws + 348160);          // 16 KB
  f16*   lut1   = (f16*)(ws + 2097152);           // 2 MB (K-tiled + pre-swizzled)
  f16*   lut2   = (f16*)(ws + 4194304);           // 2 MB
  float* y1     = (float*)(ws + 6291456);         // 12,845,056
  float* y2     = (float*)(ws + 19136512);        // 12,845,056 (end ~32 MB)

  prep_kernel<<<8321, 256, 0, stream>>>(cent1, wsub1, cent2, wsub2,
                                        g1, be1, mu1, va1, g2, be2, mu2, va2,
                                        lut1, lut2, centK1, centK2,
                                        bn1i, bn1a, bn2i, bn2a, pool);
  fused_kernel<0, true ><<<196, 512, 0, stream>>>(x,  centK1, lut1, bn1i, bn1a, y1);
  fused_kernel<1, false><<<196, 512, 0, stream>>>(y1, centK2, lut2, bn2i, bn2a, y2);
  pool_kernel<<<dim3(16, 7), 256, 0, stream>>>(y2, pool);
  se_kernel<<<16, 256, 0, stream>>>(pool, sw1, sb1, sw2, sb2, scale);
  final_kernel<<<12544, 256, 0, stream>>>(y2, scale, x, out);
}